// Round 6
// baseline (385.466 us; speedup 1.0000x reference)
//
#include <hip/hip_runtime.h>
#include <hip/hip_bf16.h>
#include <math.h>

#define LP 1000
#define NCMP 64

__device__ __forceinline__ float rcp_fast(float x) { return __builtin_amdgcn_rcpf(x); }

// ---------------- 32-row GEMM body (used only by tiny pre0 kernel) ----------------
template<bool RELU_IN>
__device__ __forceinline__ void gemm_body(const float* X, const float* W, const float* __restrict__ bias,
                                          float* Y, int K, int rowbase)
{
    __shared__ __align__(16) float Ws[32][128];
    __shared__ __align__(16) float Xt[32][36];
    const int t  = threadIdx.x;
    const int r0 = (t >> 5) * 4;
    const int c0 = (t & 31) * 4;
    const int xr = t >> 3, xk = (t & 7) << 2;
    const int xrow = rowbase + xr;
    float4 xv = *(const float4*)(X + (long)xrow * K + xk);
    float4 wv[4];
    #pragma unroll
    for (int u = 0; u < 4; ++u) {
        int s = t + u * 256, r = s >> 5, cb = (s & 31) << 2;
        wv[u] = *(const float4*)(W + (long)r * 128 + cb);
    }
    float acc[4][4] = {};
    for (int k0 = 0; k0 < K; k0 += 32) {
        if (RELU_IN) { xv.x = fmaxf(xv.x,0.f); xv.y = fmaxf(xv.y,0.f);
                       xv.z = fmaxf(xv.z,0.f); xv.w = fmaxf(xv.w,0.f); }
        Xt[xk+0][xr] = xv.x; Xt[xk+1][xr] = xv.y; Xt[xk+2][xr] = xv.z; Xt[xk+3][xr] = xv.w;
        #pragma unroll
        for (int u = 0; u < 4; ++u) {
            int s = t + u * 256, r = s >> 5, cb = (s & 31) << 2;
            *(float4*)&Ws[r][cb] = wv[u];
        }
        __syncthreads();
        if (k0 + 32 < K) {
            xv = *(const float4*)(X + (long)xrow * K + k0 + 32 + xk);
            #pragma unroll
            for (int u = 0; u < 4; ++u) {
                int s = t + u * 256, r = s >> 5, cb = (s & 31) << 2;
                wv[u] = *(const float4*)(W + (long)(k0 + 32 + r) * 128 + cb);
            }
        }
        #pragma unroll
        for (int kk = 0; kk < 32; ++kk) {
            float4 w4 = *(const float4*)&Ws[kk][c0];
            float4 x4 = *(const float4*)&Xt[kk][r0];
            acc[0][0] = fmaf(x4.x, w4.x, acc[0][0]); acc[0][1] = fmaf(x4.x, w4.y, acc[0][1]);
            acc[0][2] = fmaf(x4.x, w4.z, acc[0][2]); acc[0][3] = fmaf(x4.x, w4.w, acc[0][3]);
            acc[1][0] = fmaf(x4.y, w4.x, acc[1][0]); acc[1][1] = fmaf(x4.y, w4.y, acc[1][1]);
            acc[1][2] = fmaf(x4.y, w4.z, acc[1][2]); acc[1][3] = fmaf(x4.y, w4.w, acc[1][3]);
            acc[2][0] = fmaf(x4.z, w4.x, acc[2][0]); acc[2][1] = fmaf(x4.z, w4.y, acc[2][1]);
            acc[2][2] = fmaf(x4.z, w4.z, acc[2][2]); acc[2][3] = fmaf(x4.z, w4.w, acc[2][3]);
            acc[3][0] = fmaf(x4.w, w4.x, acc[3][0]); acc[3][1] = fmaf(x4.w, w4.y, acc[3][1]);
            acc[3][2] = fmaf(x4.w, w4.z, acc[3][2]); acc[3][3] = fmaf(x4.w, w4.w, acc[3][3]);
        }
        __syncthreads();
    }
    float4 bv = *(const float4*)(bias + c0);
    #pragma unroll
    for (int i = 0; i < 4; ++i) {
        int row = rowbase + r0 + i;
        float4 o;
        o.x = acc[i][0] + bv.x; o.y = acc[i][1] + bv.y;
        o.z = acc[i][2] + bv.z; o.w = acc[i][3] + bv.w;
        *(float4*)(Y + (long)row * 128 + c0) = o;
    }
}

// ---------------- pre0: W' = emb_w @ wq_w (blocks 0-9), b' = emb_b@wq_w + wq_b (block 10) ----
__global__ __launch_bounds__(256) void pre0_k(const float* __restrict__ emb_w, const float* __restrict__ emb_b,
                                              const float* __restrict__ wq_w, const float* __restrict__ wq_b,
                                              const float* __restrict__ zeros,
                                              float* __restrict__ Wp, float* __restrict__ bp)
{
    if (blockIdx.x == 10) {
        int n = threadIdx.x;
        if (n < 128) {
            float a0 = 0.f, a1 = 0.f, a2 = 0.f, a3 = 0.f;
            for (int k = 0; k < 128; k += 4) {
                a0 = fmaf(emb_b[k+0], wq_w[(k+0)*128 + n], a0);
                a1 = fmaf(emb_b[k+1], wq_w[(k+1)*128 + n], a1);
                a2 = fmaf(emb_b[k+2], wq_w[(k+2)*128 + n], a2);
                a3 = fmaf(emb_b[k+3], wq_w[(k+3)*128 + n], a3);
            }
            bp[n] = (a0 + a1) + (a2 + a3) + wq_b[n];
        }
        return;
    }
    gemm_body<false>(emb_w, wq_w, zeros, Wp, 128, blockIdx.x * 32);
}

// ---------------- qkv: Q 16-row tiles (blocks 0-499) + KV 16x256 tiles (500-999) ----------------
__global__ __launch_bounds__(256) void qkv_k(const float* __restrict__ PE, const float* __restrict__ Wp,
                                             const float* __restrict__ bp, const float* __restrict__ PFX,
                                             const float* __restrict__ wk_w, const float* __restrict__ wv_w,
                                             const float* __restrict__ wk_b, const float* __restrict__ wv_b,
                                             float* __restrict__ Qo, float* __restrict__ Ko, float* __restrict__ Vo)
{
    __shared__ __align__(16) float Ws[32][256];
    __shared__ __align__(16) float Xt[32][20];
    const int t = threadIdx.x;
    if (blockIdx.x < 500) {
        // ---- Q = PE @ W' + b'   (16x128 tile, K=320, thread 2r x 4c) ----
        const int rowbase = blockIdx.x * 16;
        const int r0 = (t >> 5) * 2, c0 = (t & 31) * 4;
        const int xr = t >> 3, xk = (t & 7) << 2;
        float4 xv; float4 wv[4];
        if (t < 128) xv = *(const float4*)(PE + (long)(rowbase + xr) * 320 + xk);
        #pragma unroll
        for (int u = 0; u < 4; ++u) {
            int s = t + u * 256, r = s >> 5, cb = (s & 31) << 2;
            wv[u] = *(const float4*)(Wp + (long)r * 128 + cb);
        }
        float acc[2][4] = {};
        for (int k0 = 0; k0 < 320; k0 += 32) {
            if (t < 128) { Xt[xk+0][xr]=xv.x; Xt[xk+1][xr]=xv.y; Xt[xk+2][xr]=xv.z; Xt[xk+3][xr]=xv.w; }
            #pragma unroll
            for (int u = 0; u < 4; ++u) {
                int s = t + u * 256, r = s >> 5, cb = (s & 31) << 2;
                *(float4*)&Ws[r][cb] = wv[u];
            }
            __syncthreads();
            if (k0 + 32 < 320) {
                if (t < 128) xv = *(const float4*)(PE + (long)(rowbase + xr) * 320 + k0 + 32 + xk);
                #pragma unroll
                for (int u = 0; u < 4; ++u) {
                    int s = t + u * 256, r = s >> 5, cb = (s & 31) << 2;
                    wv[u] = *(const float4*)(Wp + (long)(k0 + 32 + r) * 128 + cb);
                }
            }
            #pragma unroll
            for (int kk = 0; kk < 32; ++kk) {
                float2 x2 = *(const float2*)&Xt[kk][r0];
                float4 w4 = *(const float4*)&Ws[kk][c0];
                acc[0][0]=fmaf(x2.x,w4.x,acc[0][0]); acc[0][1]=fmaf(x2.x,w4.y,acc[0][1]);
                acc[0][2]=fmaf(x2.x,w4.z,acc[0][2]); acc[0][3]=fmaf(x2.x,w4.w,acc[0][3]);
                acc[1][0]=fmaf(x2.y,w4.x,acc[1][0]); acc[1][1]=fmaf(x2.y,w4.y,acc[1][1]);
                acc[1][2]=fmaf(x2.y,w4.z,acc[1][2]); acc[1][3]=fmaf(x2.y,w4.w,acc[1][3]);
            }
            __syncthreads();
        }
        float4 bv = *(const float4*)(bp + c0);
        #pragma unroll
        for (int i = 0; i < 2; ++i) {
            float4 o;
            o.x = acc[i][0]+bv.x; o.y = acc[i][1]+bv.y; o.z = acc[i][2]+bv.z; o.w = acc[i][3]+bv.w;
            *(float4*)(Qo + (long)(rowbase + r0 + i) * 128 + c0) = o;
        }
    } else {
        // ---- K|V = PFX @ [wk|wv] + b   (16x256 tile, K=128, thread 4r x 4c) ----
        const int rowbase = (blockIdx.x - 500) * 16;
        const int r0 = (t >> 6) * 4, c0 = (t & 63) * 4;
        const int xr = t >> 3, xk = (t & 7) << 2;
        float4 xv; float4 wv[8];
        if (t < 128) xv = *(const float4*)(PFX + (long)(rowbase + xr) * 128 + xk);
        #pragma unroll
        for (int u = 0; u < 8; ++u) {
            int s = t + u * 256, r = s >> 6, cb = (s & 63) << 2;
            wv[u] = (cb < 128) ? *(const float4*)(wk_w + (long)r * 128 + cb)
                               : *(const float4*)(wv_w + (long)r * 128 + cb - 128);
        }
        float acc[4][4] = {};
        for (int k0 = 0; k0 < 128; k0 += 32) {
            if (t < 128) { Xt[xk+0][xr]=xv.x; Xt[xk+1][xr]=xv.y; Xt[xk+2][xr]=xv.z; Xt[xk+3][xr]=xv.w; }
            #pragma unroll
            for (int u = 0; u < 8; ++u) {
                int s = t + u * 256, r = s >> 6, cb = (s & 63) << 2;
                *(float4*)&Ws[r][cb] = wv[u];
            }
            __syncthreads();
            if (k0 + 32 < 128) {
                if (t < 128) xv = *(const float4*)(PFX + (long)(rowbase + xr) * 128 + k0 + 32 + xk);
                #pragma unroll
                for (int u = 0; u < 8; ++u) {
                    int s = t + u * 256, r = s >> 6, cb = (s & 63) << 2;
                    wv[u] = (cb < 128) ? *(const float4*)(wk_w + (long)(k0 + 32 + r) * 128 + cb)
                                       : *(const float4*)(wv_w + (long)(k0 + 32 + r) * 128 + cb - 128);
                }
            }
            #pragma unroll
            for (int kk = 0; kk < 32; ++kk) {
                float4 x4 = *(const float4*)&Xt[kk][r0];
                float4 w4 = *(const float4*)&Ws[kk][c0];
                acc[0][0]=fmaf(x4.x,w4.x,acc[0][0]); acc[0][1]=fmaf(x4.x,w4.y,acc[0][1]);
                acc[0][2]=fmaf(x4.x,w4.z,acc[0][2]); acc[0][3]=fmaf(x4.x,w4.w,acc[0][3]);
                acc[1][0]=fmaf(x4.y,w4.x,acc[1][0]); acc[1][1]=fmaf(x4.y,w4.y,acc[1][1]);
                acc[1][2]=fmaf(x4.y,w4.z,acc[1][2]); acc[1][3]=fmaf(x4.y,w4.w,acc[1][3]);
                acc[2][0]=fmaf(x4.z,w4.x,acc[2][0]); acc[2][1]=fmaf(x4.z,w4.y,acc[2][1]);
                acc[2][2]=fmaf(x4.z,w4.z,acc[2][2]); acc[2][3]=fmaf(x4.z,w4.w,acc[2][3]);
                acc[3][0]=fmaf(x4.w,w4.x,acc[3][0]); acc[3][1]=fmaf(x4.w,w4.y,acc[3][1]);
                acc[3][2]=fmaf(x4.w,w4.z,acc[3][2]); acc[3][3]=fmaf(x4.w,w4.w,acc[3][3]);
            }
            __syncthreads();
        }
        const bool isK = (c0 < 128);
        const int cc = isK ? c0 : c0 - 128;
        float4 bv = isK ? *(const float4*)(wk_b + cc) : *(const float4*)(wv_b + cc);
        float* Y = isK ? Ko : Vo;
        #pragma unroll
        for (int i = 0; i < 4; ++i) {
            float4 o;
            o.x = acc[i][0]+bv.x; o.y = acc[i][1]+bv.y; o.z = acc[i][2]+bv.z; o.w = acc[i][3]+bv.w;
            *(float4*)(Y + (long)(rowbase + r0 + i) * 128 + cc) = o;
        }
    }
}

// ---------------- flash attention v4: TQ=64, TK=64, sp=4 splits, 256 threads, 4r x 4c ----------
// Q read from global (16-way lane broadcast, L1). K,V register-prefetched across barriers.
// LDS = KVs 33.8K + Pt 17.4K = 51.2 KB -> 2-3 blocks/CU (8-12 waves/CU).
__global__ __launch_bounds__(256) void flash4_k(const float* __restrict__ Q, const float* __restrict__ Kg,
                                                const float* __restrict__ Vg, float* __restrict__ Opart,
                                                float* __restrict__ mpart, float* __restrict__ lpart)
{
    __shared__ __align__(16) float KVs[64][132];
    __shared__ __align__(16) float Pt[64][68];
    const int t  = threadIdx.x;
    const int rg = t >> 4;        // 0..15 -> rows 4rg..4rg+3
    const int cl = t & 15;        // cols cl+16j
    const int qt = blockIdx.x, sp = blockIdx.y, b = blockIdx.z;
    const int q0 = qt * 64;
    const float SCALE = 0.08838834764831845f;   // 1/sqrt(128)
    const float L2E   = 1.4426950408889634f;
    const float* Qb = Q + ((long)b * LP + q0 + 4 * rg) * 128;   // rows >=LP read in-ws garbage, masked at store

    float m_i[4] = {-3.0e38f,-3.0e38f,-3.0e38f,-3.0e38f};
    float l_i[4] = {0.f,0.f,0.f,0.f};
    float Oa[4][8] = {};
    float4 kreg[8], vreg[8];
    {   // prologue: K prefetch for first kt
        const int key0 = sp * 256;
        #pragma unroll
        for (int u = 0; u < 8; ++u) {
            int s = t + u * 256, r = s >> 5, cb = (s & 31) << 2;
            kreg[u] = make_float4(0.f,0.f,0.f,0.f);
            if (key0 + r < LP) kreg[u] = *(const float4*)(Kg + ((long)b * LP + key0 + r) * 128 + cb);
        }
    }
    for (int kt = sp * 4; kt < sp * 4 + 4; ++kt) {
        const int key0 = kt * 64;
        __syncthreads();                               // (A) prev PV done with KVs/Pt
        #pragma unroll
        for (int u = 0; u < 8; ++u) {                  // K regs -> LDS
            int s = t + u * 256, r = s >> 5, cb = (s & 31) << 2;
            KVs[r][cb] = kreg[u].x; KVs[r][cb+1] = kreg[u].y;
            KVs[r][cb+2] = kreg[u].z; KVs[r][cb+3] = kreg[u].w;
        }
        __syncthreads();                               // (B) K visible
        #pragma unroll
        for (int u = 0; u < 8; ++u) {                  // V prefetch (drains under QK)
            int s = t + u * 256, r = s >> 5, cb = (s & 31) << 2;
            vreg[u] = make_float4(0.f,0.f,0.f,0.f);
            if (key0 + r < LP) vreg[u] = *(const float4*)(Vg + ((long)b * LP + key0 + r) * 128 + cb);
        }
        float sacc[4][4] = {};
        #pragma unroll 4
        for (int d4 = 0; d4 < 32; ++d4) {
            float4 q0v = *(const float4*)(Qb + 0 * 128 + (d4 << 2));
            float4 q1v = *(const float4*)(Qb + 1 * 128 + (d4 << 2));
            float4 q2v = *(const float4*)(Qb + 2 * 128 + (d4 << 2));
            float4 q3v = *(const float4*)(Qb + 3 * 128 + (d4 << 2));
            #pragma unroll
            for (int j = 0; j < 4; ++j) {
                float4 kv = *(const float4*)&KVs[cl + (j << 4)][d4 << 2];
                sacc[0][j] += q0v.x*kv.x + q0v.y*kv.y + q0v.z*kv.z + q0v.w*kv.w;
                sacc[1][j] += q1v.x*kv.x + q1v.y*kv.y + q1v.z*kv.z + q1v.w*kv.w;
                sacc[2][j] += q2v.x*kv.x + q2v.y*kv.y + q2v.z*kv.z + q2v.w*kv.w;
                sacc[3][j] += q3v.x*kv.x + q3v.y*kv.y + q3v.z*kv.z + q3v.w*kv.w;
            }
        }
        #pragma unroll
        for (int j = 0; j < 4; ++j) {                  // scale + key mask
            bool valid = (key0 + cl + (j << 4)) < LP;
            #pragma unroll
            for (int i = 0; i < 4; ++i) {
                float sv = sacc[i][j] * SCALE;
                sacc[i][j] = valid ? sv : -3.0e38f;
            }
        }
        #pragma unroll
        for (int i = 0; i < 4; ++i) {                  // online softmax (16-lane row groups)
            float tm = fmaxf(fmaxf(sacc[i][0], sacc[i][1]), fmaxf(sacc[i][2], sacc[i][3]));
            tm = fmaxf(tm, __shfl_xor(tm, 1));
            tm = fmaxf(tm, __shfl_xor(tm, 2));
            tm = fmaxf(tm, __shfl_xor(tm, 4));
            tm = fmaxf(tm, __shfl_xor(tm, 8));
            float mnew = fmaxf(m_i[i], tm);
            float alpha = exp2f((m_i[i] - mnew) * L2E);
            float ps = 0.f;
            #pragma unroll
            for (int j = 0; j < 4; ++j) {
                float p = exp2f((sacc[i][j] - mnew) * L2E);
                sacc[i][j] = p;
                ps += p;
            }
            ps += __shfl_xor(ps, 1);
            ps += __shfl_xor(ps, 2);
            ps += __shfl_xor(ps, 4);
            ps += __shfl_xor(ps, 8);
            l_i[i] = l_i[i] * alpha + ps;
            m_i[i] = mnew;
            #pragma unroll
            for (int j = 0; j < 8; ++j) Oa[i][j] *= alpha;
        }
        __syncthreads();                               // (C) all QK reads of KVs done
        #pragma unroll
        for (int u = 0; u < 8; ++u) {                  // V regs -> LDS (overwrite K)
            int s = t + u * 256, r = s >> 5, cb = (s & 31) << 2;
            KVs[r][cb] = vreg[u].x; KVs[r][cb+1] = vreg[u].y;
            KVs[r][cb+2] = vreg[u].z; KVs[r][cb+3] = vreg[u].w;
        }
        #pragma unroll
        for (int j = 0; j < 4; ++j)                    // P -> Pt[c][rows]
            *(float4*)&Pt[cl + (j << 4)][4 * rg] =
                make_float4(sacc[0][j], sacc[1][j], sacc[2][j], sacc[3][j]);
        __syncthreads();                               // (D) V + Pt visible
        if (kt + 1 < sp * 4 + 4) {                     // K prefetch kt+1 (drains under PV)
            const int kn0 = (kt + 1) * 64;
            #pragma unroll
            for (int u = 0; u < 8; ++u) {
                int s = t + u * 256, r = s >> 5, cb = (s & 31) << 2;
                kreg[u] = make_float4(0.f,0.f,0.f,0.f);
                if (kn0 + r < LP) kreg[u] = *(const float4*)(Kg + ((long)b * LP + kn0 + r) * 128 + cb);
            }
        }
        #pragma unroll 2
        for (int c = 0; c < 64; ++c) {                 // PV
            float4 p4 = *(const float4*)&Pt[c][4 * rg];
            float4 va = *(const float4*)&KVs[c][4 * cl];
            float4 vb = *(const float4*)&KVs[c][64 + 4 * cl];
            Oa[0][0]=fmaf(p4.x,va.x,Oa[0][0]); Oa[0][1]=fmaf(p4.x,va.y,Oa[0][1]);
            Oa[0][2]=fmaf(p4.x,va.z,Oa[0][2]); Oa[0][3]=fmaf(p4.x,va.w,Oa[0][3]);
            Oa[0][4]=fmaf(p4.x,vb.x,Oa[0][4]); Oa[0][5]=fmaf(p4.x,vb.y,Oa[0][5]);
            Oa[0][6]=fmaf(p4.x,vb.z,Oa[0][6]); Oa[0][7]=fmaf(p4.x,vb.w,Oa[0][7]);
            Oa[1][0]=fmaf(p4.y,va.x,Oa[1][0]); Oa[1][1]=fmaf(p4.y,va.y,Oa[1][1]);
            Oa[1][2]=fmaf(p4.y,va.z,Oa[1][2]); Oa[1][3]=fmaf(p4.y,va.w,Oa[1][3]);
            Oa[1][4]=fmaf(p4.y,vb.x,Oa[1][4]); Oa[1][5]=fmaf(p4.y,vb.y,Oa[1][5]);
            Oa[1][6]=fmaf(p4.y,vb.z,Oa[1][6]); Oa[1][7]=fmaf(p4.y,vb.w,Oa[1][7]);
            Oa[2][0]=fmaf(p4.z,va.x,Oa[2][0]); Oa[2][1]=fmaf(p4.z,va.y,Oa[2][1]);
            Oa[2][2]=fmaf(p4.z,va.z,Oa[2][2]); Oa[2][3]=fmaf(p4.z,va.w,Oa[2][3]);
            Oa[2][4]=fmaf(p4.z,vb.x,Oa[2][4]); Oa[2][5]=fmaf(p4.z,vb.y,Oa[2][5]);
            Oa[2][6]=fmaf(p4.z,vb.z,Oa[2][6]); Oa[2][7]=fmaf(p4.z,vb.w,Oa[2][7]);
            Oa[3][0]=fmaf(p4.w,va.x,Oa[3][0]); Oa[3][1]=fmaf(p4.w,va.y,Oa[3][1]);
            Oa[3][2]=fmaf(p4.w,va.z,Oa[3][2]); Oa[3][3]=fmaf(p4.w,va.w,Oa[3][3]);
            Oa[3][4]=fmaf(p4.w,vb.x,Oa[3][4]); Oa[3][5]=fmaf(p4.w,vb.y,Oa[3][5]);
            Oa[3][6]=fmaf(p4.w,vb.z,Oa[3][6]); Oa[3][7]=fmaf(p4.w,vb.w,Oa[3][7]);
        }
    }
    #pragma unroll
    for (int i = 0; i < 4; ++i) {
        int row = q0 + 4 * rg + i;
        if (row < LP) {
            long base = (((long)sp * 8 + b) * LP + row) * 128;
            *(float4*)(Opart + base + 4 * cl)      = make_float4(Oa[i][0], Oa[i][1], Oa[i][2], Oa[i][3]);
            *(float4*)(Opart + base + 64 + 4 * cl) = make_float4(Oa[i][4], Oa[i][5], Oa[i][6], Oa[i][7]);
            if (cl == 0) {
                mpart[((long)sp * 8 + b) * LP + row] = m_i[i];
                lpart[((long)sp * 8 + b) * LP + row] = l_i[i];
            }
        }
    }
}

// ------- wojp: blocks 0-499: Att = merge4(Opart)@wo_w + b, then P = relu(Att)@jp_w + b (fused);
//         blocks 500-531: Cj = relu(CF)@jc_w + b.  16-row tiles, thread 2r x 4c. -------
__global__ __launch_bounds__(256) void wojp_k(const float* __restrict__ Opart, const float* __restrict__ mp,
                                              const float* __restrict__ lp, const float* __restrict__ wo_w,
                                              const float* __restrict__ wo_b, float* __restrict__ Att,
                                              const float* __restrict__ jp_w, const float* __restrict__ jp_b,
                                              float* __restrict__ Pout,
                                              const float* __restrict__ CF, const float* __restrict__ jc_w,
                                              const float* __restrict__ jc_b, float* __restrict__ Cj)
{
    __shared__ __align__(16) float Ws[32][128];
    __shared__ __align__(16) float Xt[32][20];
    __shared__ __align__(16) float XtF[128][20];
    const int t  = threadIdx.x;
    const int r0 = (t >> 5) * 2, c0 = (t & 31) * 4;
    const int xr = t >> 3, xk = (t & 7) << 2;
    const bool isJC = (blockIdx.x >= 500);
    const int rowbase = isJC ? (blockIdx.x - 500) * 16 : blockIdx.x * 16;
    const float L2E = 1.4426950408889634f;
    const float* W1 = isJC ? jc_w : wo_w;
    const float* b1 = isJC ? jc_b : wo_b;

    float wgt[4]; float linv = 0.f;
    const int xrow = rowbase + xr;
    if (!isJC && t < 128) {
        float m0 = mp[xrow], m1 = mp[xrow + 8000], m2 = mp[xrow + 16000], m3 = mp[xrow + 24000];
        float mm = fmaxf(fmaxf(m0, m1), fmaxf(m2, m3));
        wgt[0] = exp2f((m0 - mm) * L2E); wgt[1] = exp2f((m1 - mm) * L2E);
        wgt[2] = exp2f((m2 - mm) * L2E); wgt[3] = exp2f((m3 - mm) * L2E);
        float ls = wgt[0]*lp[xrow] + wgt[1]*lp[xrow+8000] + wgt[2]*lp[xrow+16000] + wgt[3]*lp[xrow+24000];
        linv = 1.0f / ls;
    }
    float4 xv; float4 wv[4];
    if (t < 128) {
        if (isJC) {
            xv = *(const float4*)(CF + (long)xrow * 128 + xk);
            xv.x = fmaxf(xv.x,0.f); xv.y = fmaxf(xv.y,0.f); xv.z = fmaxf(xv.z,0.f); xv.w = fmaxf(xv.w,0.f);
        } else {
            float4 a0 = *(const float4*)(Opart + ((long)xrow) * 128 + xk);
            float4 a1 = *(const float4*)(Opart + ((long)xrow + 8000) * 128 + xk);
            float4 a2 = *(const float4*)(Opart + ((long)xrow + 16000) * 128 + xk);
            float4 a3 = *(const float4*)(Opart + ((long)xrow + 24000) * 128 + xk);
            xv.x = (wgt[0]*a0.x + wgt[1]*a1.x + wgt[2]*a2.x + wgt[3]*a3.x) * linv;
            xv.y = (wgt[0]*a0.y + wgt[1]*a1.y + wgt[2]*a2.y + wgt[3]*a3.y) * linv;
            xv.z = (wgt[0]*a0.z + wgt[1]*a1.z + wgt[2]*a2.z + wgt[3]*a3.z) * linv;
            xv.w = (wgt[0]*a0.w + wgt[1]*a1.w + wgt[2]*a2.w + wgt[3]*a3.w) * linv;
        }
    }
    #pragma unroll
    for (int u = 0; u < 4; ++u) {
        int s = t + u * 256, r = s >> 5, cb = (s & 31) << 2;
        wv[u] = *(const float4*)(W1 + (long)r * 128 + cb);
    }
    float acc[2][4] = {};
    for (int k0 = 0; k0 < 128; k0 += 32) {
        if (t < 128) { Xt[xk+0][xr]=xv.x; Xt[xk+1][xr]=xv.y; Xt[xk+2][xr]=xv.z; Xt[xk+3][xr]=xv.w; }
        #pragma unroll
        for (int u = 0; u < 4; ++u) {
            int s = t + u * 256, r = s >> 5, cb = (s & 31) << 2;
            *(float4*)&Ws[r][cb] = wv[u];
        }
        __syncthreads();
        if (k0 + 32 < 128) {
            int kn = k0 + 32;
            if (t < 128) {
                if (isJC) {
                    xv = *(const float4*)(CF + (long)xrow * 128 + kn + xk);
                    xv.x = fmaxf(xv.x,0.f); xv.y = fmaxf(xv.y,0.f); xv.z = fmaxf(xv.z,0.f); xv.w = fmaxf(xv.w,0.f);
                } else {
                    float4 a0 = *(const float4*)(Opart + ((long)xrow) * 128 + kn + xk);
                    float4 a1 = *(const float4*)(Opart + ((long)xrow + 8000) * 128 + kn + xk);
                    float4 a2 = *(const float4*)(Opart + ((long)xrow + 16000) * 128 + kn + xk);
                    float4 a3 = *(const float4*)(Opart + ((long)xrow + 24000) * 128 + kn + xk);
                    xv.x = (wgt[0]*a0.x + wgt[1]*a1.x + wgt[2]*a2.x + wgt[3]*a3.x) * linv;
                    xv.y = (wgt[0]*a0.y + wgt[1]*a1.y + wgt[2]*a2.y + wgt[3]*a3.y) * linv;
                    xv.z = (wgt[0]*a0.z + wgt[1]*a1.z + wgt[2]*a2.z + wgt[3]*a3.z) * linv;
                    xv.w = (wgt[0]*a0.w + wgt[1]*a1.w + wgt[2]*a2.w + wgt[3]*a3.w) * linv;
                }
            }
            #pragma unroll
            for (int u = 0; u < 4; ++u) {
                int s = t + u * 256, r = s >> 5, cb = (s & 31) << 2;
                wv[u] = *(const float4*)(W1 + (long)(kn + r) * 128 + cb);
            }
        }
        #pragma unroll
        for (int kk = 0; kk < 32; ++kk) {
            float2 x2 = *(const float2*)&Xt[kk][r0];
            float4 w4 = *(const float4*)&Ws[kk][c0];
            acc[0][0]=fmaf(x2.x,w4.x,acc[0][0]); acc[0][1]=fmaf(x2.x,w4.y,acc[0][1]);
            acc[0][2]=fmaf(x2.x,w4.z,acc[0][2]); acc[0][3]=fmaf(x2.x,w4.w,acc[0][3]);
            acc[1][0]=fmaf(x2.y,w4.x,acc[1][0]); acc[1][1]=fmaf(x2.y,w4.y,acc[1][1]);
            acc[1][2]=fmaf(x2.y,w4.z,acc[1][2]); acc[1][3]=fmaf(x2.y,w4.w,acc[1][3]);
        }
        __syncthreads();
    }
    float4 bv = *(const float4*)(b1 + c0);
    #pragma unroll
    for (int i = 0; i < 2; ++i) { acc[i][0]+=bv.x; acc[i][1]+=bv.y; acc[i][2]+=bv.z; acc[i][3]+=bv.w; }
    if (isJC) {
        #pragma unroll
        for (int i = 0; i < 2; ++i)
            *(float4*)(Cj + (long)(rowbase + r0 + i) * 128 + c0) =
                make_float4(acc[i][0], acc[i][1], acc[i][2], acc[i][3]);
        return;
    }
    #pragma unroll
    for (int i = 0; i < 2; ++i)
        *(float4*)(Att + (long)(rowbase + r0 + i) * 128 + c0) =
            make_float4(acc[i][0], acc[i][1], acc[i][2], acc[i][3]);
    #pragma unroll
    for (int q = 0; q < 4; ++q)   // relu(Att) -> XtF[col][row] for the jp gemm
        *(float2*)&XtF[c0 + q][r0] = make_float2(fmaxf(acc[0][q], 0.f), fmaxf(acc[1][q], 0.f));
    // ---- second pass: P = relu(Att) @ jp_w + jp_b ----
    float4 wv2[4];
    #pragma unroll
    for (int u = 0; u < 4; ++u) {
        int s = t + u * 256, r = s >> 5, cb = (s & 31) << 2;
        wv2[u] = *(const float4*)(jp_w + (long)r * 128 + cb);
    }
    float ac2[2][4] = {};
    for (int k0 = 0; k0 < 128; k0 += 32) {
        #pragma unroll
        for (int u = 0; u < 4; ++u) {
            int s = t + u * 256, r = s >> 5, cb = (s & 31) << 2;
            *(float4*)&Ws[r][cb] = wv2[u];
        }
        __syncthreads();
        if (k0 + 32 < 128) {
            #pragma unroll
            for (int u = 0; u < 4; ++u) {
                int s = t + u * 256, r = s >> 5, cb = (s & 31) << 2;
                wv2[u] = *(const float4*)(jp_w + (long)(k0 + 32 + r) * 128 + cb);
            }
        }
        #pragma unroll
        for (int kk = 0; kk < 32; ++kk) {
            float2 x2 = *(const float2*)&XtF[k0 + kk][r0];
            float4 w4 = *(const float4*)&Ws[kk][c0];
            ac2[0][0]=fmaf(x2.x,w4.x,ac2[0][0]); ac2[0][1]=fmaf(x2.x,w4.y,ac2[0][1]);
            ac2[0][2]=fmaf(x2.x,w4.z,ac2[0][2]); ac2[0][3]=fmaf(x2.x,w4.w,ac2[0][3]);
            ac2[1][0]=fmaf(x2.y,w4.x,ac2[1][0]); ac2[1][1]=fmaf(x2.y,w4.y,ac2[1][1]);
            ac2[1][2]=fmaf(x2.y,w4.z,ac2[1][2]); ac2[1][3]=fmaf(x2.y,w4.w,ac2[1][3]);
        }
        __syncthreads();
    }
    float4 b2 = *(const float4*)(jp_b + c0);
    #pragma unroll
    for (int i = 0; i < 2; ++i)
        *(float4*)(Pout + (long)(rowbase + r0 + i) * 128 + c0) =
            make_float4(ac2[i][0]+b2.x, ac2[i][1]+b2.y, ac2[i][2]+b2.z, ac2[i][3]+b2.w);
}

// -------- fused: A = sigmoid(P C^T) in LDS + Asum + tanh outer-product reduce (16-row tiles) -----
__global__ __launch_bounds__(256) void sigcp_k(const float* __restrict__ P, const float* __restrict__ Cj,
                                               const float* __restrict__ pf, const float* __restrict__ cf,
                                               float* __restrict__ Asum, float* __restrict__ cpe)
{
    __shared__ __align__(16) float Psh[16][132];
    __shared__ __align__(16) float Csh[64][132];
    __shared__ float Ash[16][64];
    __shared__ float red[256];
    const int t  = threadIdx.x;
    const int tr = t >> 4, tc = t & 15;     // 1 row x 4 cols
    const int i0 = blockIdx.x * 16;
    const int b  = blockIdx.y;
    #pragma unroll
    for (int u = 0; u < 2; ++u) {
        int s = t + u * 256, r = s >> 5, cb = (s & 31) << 2;
        float4 v = make_float4(0.f,0.f,0.f,0.f);
        if (i0 + r < LP) v = *(const float4*)(P + ((long)b * LP + i0 + r) * 128 + cb);
        Psh[r][cb] = v.x; Psh[r][cb+1] = v.y; Psh[r][cb+2] = v.z; Psh[r][cb+3] = v.w;
    }
    #pragma unroll
    for (int u = 0; u < 8; ++u) {
        int s = t + u * 256, r = s >> 5, cb = (s & 31) << 2;
        float4 v = *(const float4*)(Cj + ((long)b * NCMP + r) * 128 + cb);
        Csh[r][cb] = v.x; Csh[r][cb+1] = v.y; Csh[r][cb+2] = v.z; Csh[r][cb+3] = v.w;
    }
    __syncthreads();
    float sacc[4] = {};
    #pragma unroll 4
    for (int d4 = 0; d4 < 32; ++d4) {
        float4 p0 = *(const float4*)&Psh[tr][d4 << 2];
        #pragma unroll
        for (int j = 0; j < 4; ++j) {
            float4 cv = *(const float4*)&Csh[tc + (j << 4)][d4 << 2];
            sacc[j] += p0.x*cv.x + p0.y*cv.y + p0.z*cv.z + p0.w*cv.w;
        }
    }
    const float L2E = 1.4426950408889634f;
    float lsum = 0.f;
    {
        int gi = i0 + tr;
        #pragma unroll
        for (int j = 0; j < 4; ++j) {
            float sg = rcp_fast(1.f + exp2f(-sacc[j] * L2E));
            if (gi < LP) { Ash[tr][tc + (j << 4)] = sg; lsum += sg; }
        }
    }
    red[t] = lsum;
    __syncthreads();
    for (int off = 128; off > 0; off >>= 1) {
        if (t < off) red[t] += red[t + off];
        __syncthreads();
    }
    if (t == 0) atomicAdd(Asum + b, red[0]);
    __syncthreads();
    #pragma unroll
    for (int u = 0; u < 8; ++u) {                      // reload Csh with raw compound feats
        int s = t + u * 256, r = s >> 5, cb = (s & 31) << 2;
        float4 v = *(const float4*)(cf + ((long)b * NCMP + r) * 128 + cb);
        Csh[r][cb] = v.x; Csh[r][cb+1] = v.y; Csh[r][cb+2] = v.z; Csh[r][cb+3] = v.w;
    }
    __syncthreads();
    const float TWO_L2E = 2.8853900817779268f;   // 2*log2(e)
    const int d  = t & 127;
    const int kh = t >> 7;
    const int iiN = (LP - i0 < 16) ? (LP - i0) : 16;
    float acc = 0.f;
    for (int ii = 0; ii < iiN; ++ii) {
        float pv  = pf[((long)b * LP + i0 + ii) * 128 + d];
        float ptl = pv * TWO_L2E;
        #pragma unroll
        for (int kk = 0; kk < 32; ++kk) {
            int k = (kh << 5) + kk;
            float e  = exp2f(ptl * Csh[k][d]);          // exp(2x)
            float th = 1.f - 2.f * rcp_fast(e + 1.f);   // tanh(x)
            acc = fmaf(th, Ash[ii][k], acc);
        }
    }
    red[t] = acc;
    __syncthreads();
    if (t < 128) atomicAdd(cpe + (long)b * 128 + t, red[t] + red[t + 128]);
}

// ---------------- classifier head ----------------
__global__ __launch_bounds__(256) void c1h_k(const float* __restrict__ cpe, const float* __restrict__ Asum,
                                             const float* __restrict__ W, const float* __restrict__ bias,
                                             float* __restrict__ h1)
{
    __shared__ float sc[8][128];
    const int t = threadIdx.x;
    #pragma unroll
    for (int u = 0; u < 4; ++u) {
        int idx = t + u * 256;
        sc[idx >> 7][idx & 127] = cpe[idx] * rcp_fast(Asum[idx >> 7]);
    }
    __syncthreads();
    const int b = t >> 5, n = blockIdx.x * 32 + (t & 31);
    float a0 = 0.f, a1 = 0.f, a2 = 0.f, a3 = 0.f;
    #pragma unroll 8
    for (int k = 0; k < 128; k += 4) {
        a0 = fmaf(sc[b][k+0], W[(long)(k+0)*1024 + n], a0);
        a1 = fmaf(sc[b][k+1], W[(long)(k+1)*1024 + n], a1);
        a2 = fmaf(sc[b][k+2], W[(long)(k+2)*1024 + n], a2);
        a3 = fmaf(sc[b][k+3], W[(long)(k+3)*1024 + n], a3);
    }
    h1[b * 1024 + n] = fmaxf((a0 + a1) + (a2 + a3) + bias[n], 0.f);
}

__global__ __launch_bounds__(256) void c2_part_k(const float* __restrict__ in, const float* __restrict__ W,
                                                 float* __restrict__ part)
{
    __shared__ float ins[8][16];
    const int t = threadIdx.x, ks = blockIdx.x, k0 = ks * 16;
    if (t < 128) {
        int b = t >> 4, kk = t & 15;
        ins[b][kk] = in[b * 1024 + k0 + kk];
    }
    __syncthreads();
    const int n = (t & 63) * 4 + (t >> 6) * 256;
    float4 acc[8] = {};
    #pragma unroll
    for (int kk = 0; kk < 16; ++kk) {
        float4 w4 = *(const float4*)(W + (long)(k0 + kk) * 1024 + n);
        #pragma unroll
        for (int b = 0; b < 8; ++b) {
            float s = ins[b][kk];
            acc[b].x = fmaf(s, w4.x, acc[b].x); acc[b].y = fmaf(s, w4.y, acc[b].y);
            acc[b].z = fmaf(s, w4.z, acc[b].z); acc[b].w = fmaf(s, w4.w, acc[b].w);
        }
    }
    #pragma unroll
    for (int b = 0; b < 8; ++b)
        *(float4*)(part + ((long)(ks * 8 + b)) * 1024 + n) = acc[b];
}

__global__ __launch_bounds__(256) void c3m_k(const float* __restrict__ part2, const float* __restrict__ c2_b,
                                             const float* __restrict__ c3_w, const float* __restrict__ c3_b,
                                             const float* __restrict__ c4_w, const float* __restrict__ c4_b,
                                             float* __restrict__ out)
{
    __shared__ float Hs[1024];
    __shared__ float red[256];
    const int t = threadIdx.x, b = blockIdx.x;
    float4 acc4 = make_float4(0.f,0.f,0.f,0.f);
    #pragma unroll 4
    for (int ks = 0; ks < 64; ++ks) {
        float4 p = *(const float4*)(part2 + ((long)(ks * 8 + b)) * 1024 + t * 4);
        acc4.x += p.x; acc4.y += p.y; acc4.z += p.z; acc4.w += p.w;
    }
    {
        float4 bb = *(const float4*)(c2_b + t * 4);
        Hs[t*4+0] = fmaxf(acc4.x + bb.x, 0.f);
        Hs[t*4+1] = fmaxf(acc4.y + bb.y, 0.f);
        Hs[t*4+2] = fmaxf(acc4.z + bb.z, 0.f);
        Hs[t*4+3] = fmaxf(acc4.w + bb.w, 0.f);
    }
    __syncthreads();
    float a0 = 0.f, a1 = 0.f, a2 = 0.f, a3 = 0.f;
    #pragma unroll 8
    for (int k = 0; k < 1024; k += 4) {
        a0 = fmaf(Hs[k+0], c3_w[(long)(k+0)*256 + t], a0);
        a1 = fmaf(Hs[k+1], c3_w[(long)(k+1)*256 + t], a1);
        a2 = fmaf(Hs[k+2], c3_w[(long)(k+2)*256 + t], a2);
        a3 = fmaf(Hs[k+3], c3_w[(long)(k+3)*256 + t], a3);
    }
    float h3v = fmaxf((a0 + a1) + (a2 + a3) + c3_b[t], 0.f);
    red[t] = h3v * c4_w[t];
    __syncthreads();
    for (int off = 128; off > 0; off >>= 1) {
        if (t < off) red[t] += red[t + off];
        __syncthreads();
    }
    if (t == 0) out[b] = red[0] + c4_b[0];
}

extern "C" void kernel_launch(void* const* d_in, const int* in_sizes, int n_in,
                              void* d_out, int out_size, void* d_ws, size_t ws_size,
                              hipStream_t stream)
{
    const float* PE   = (const float*)d_in[0];
    const float* PFX  = (const float*)d_in[1];
    const float* CF   = (const float*)d_in[2];
    const float* emb_w = (const float*)d_in[3];  const float* emb_b = (const float*)d_in[4];
    const float* wq_w  = (const float*)d_in[5];  const float* wq_b  = (const float*)d_in[6];
    const float* wk_w  = (const float*)d_in[7];  const float* wk_b  = (const float*)d_in[8];
    const float* wv_w  = (const float*)d_in[9];  const float* wv_b  = (const float*)d_in[10];
    const float* wo_w  = (const float*)d_in[11]; const float* wo_b  = (const float*)d_in[12];
    const float* jp_w  = (const float*)d_in[13]; const float* jp_b  = (const float*)d_in[14];
    const float* jc_w  = (const float*)d_in[15]; const float* jc_b  = (const float*)d_in[16];
    const float* c1_w  = (const float*)d_in[17]; const float* c1_b  = (const float*)d_in[18];
    const float* c2_w  = (const float*)d_in[19]; const float* c2_b  = (const float*)d_in[20];
    const float* c3_w  = (const float*)d_in[21]; const float* c3_b  = (const float*)d_in[22];
    const float* c4_w  = (const float*)d_in[23]; const float* c4_b  = (const float*)d_in[24];

    float* ws     = (float*)d_ws;
    float* bufQ   = ws;                    // 1,024,000 (Q; later jp-out alias; later c2 partials alias)
    float* bufK   = bufQ   + 1024000;      // 1,024,000
    float* bufV   = bufK   + 1024000;      // 1,024,000
    float* bufAtt = bufV   + 1024000;      // 1,024,000 (protein_feats)
    float* bufC   = bufAtt + 1024000;      //    65,536
    float* Opart  = bufC   + 65536;        // 4,096,000 (4-way flash partials)
    float* mpart  = Opart  + 4096000;      //    32,000
    float* lpart  = mpart  + 32000;        //    32,000
    float* Asum   = lpart  + 32000;        //         8
    float* cpe    = Asum   + 8;            //     1,024
    float* zeros  = cpe    + 1024;         //       128
    float* bprime = zeros  + 128;          //       128
    float* bufWp  = bprime + 128;          //    40,960  (emb_w @ wq_w)
    float* h1     = bufWp  + 40960;        //     8,192
    float* bufP   = bufQ;                  // jp output aliases bufQ (Q dead after flash)
    float* part2  = bufQ;                  // c2 partials alias bufQ (bufP dead after sigcp)
    // total ~8.37M floats = ~33.5 MB

    hipMemsetAsync(Asum, 0, (8 + 1024 + 128) * sizeof(float), stream);   // Asum, cpe, zeros

    pre0_k<<<11, 256, 0, stream>>>(emb_w, emb_b, wq_w, wq_b, zeros, bufWp, bprime);
    qkv_k<<<1000, 256, 0, stream>>>(PE, bufWp, bprime, PFX, wk_w, wv_w, wk_b, wv_b,
                                    bufQ, bufK, bufV);
    flash4_k<<<dim3(16, 4, 8), 256, 0, stream>>>(bufQ, bufK, bufV, Opart, mpart, lpart);
    wojp_k<<<532, 256, 0, stream>>>(Opart, mpart, lpart, wo_w, wo_b, bufAtt,
                                    jp_w, jp_b, bufP, CF, jc_w, jc_b, bufC);
    sigcp_k<<<dim3(63, 8), 256, 0, stream>>>(bufP, bufC, bufAtt, CF, Asum, cpe);
    c1h_k<<<32, 256, 0, stream>>>(cpe, Asum, c1_w, c1_b, h1);
    c2_part_k<<<64, 256, 0, stream>>>(h1, c2_w, part2);
    c3m_k<<<8, 256, 0, stream>>>(part2, c2_b, c3_w, c3_b, c4_w, c4_b, (float*)d_out);
}